// Round 1
// baseline (5846.724 us; speedup 1.0000x reference)
//
#include <hip/hip_runtime.h>
#include <hip/hip_bf16.h>
#include <hip/hip_cooperative_groups.h>

namespace cg = cooperative_groups;

// Problem dims (fixed)
#define B_ 32
#define S_ 64
#define H_ 512
#define T_ 32
#define V_ 32000

typedef __attribute__((ext_vector_type(8))) short bf16x8;
typedef __attribute__((ext_vector_type(4))) float f32x4;

static __device__ __forceinline__ unsigned short f2bf(float f) {
    unsigned int u = __float_as_uint(f);
    u += 0x7FFF + ((u >> 16) & 1);   // RNE
    return (unsigned short)(u >> 16);
}
static __device__ __forceinline__ float dot4(float4 a, float4 b) {
    return a.x * b.x + a.y * b.y + a.z * b.z + a.w * b.w;
}
static __device__ __forceinline__ float tanh_fast(float x) {
    x = fminf(fmaxf(x, -15.f), 15.f);
    float e = __expf(2.f * x);
    return (e - 1.f) / (e + 1.f);
}
static __device__ __forceinline__ float sigmoid_fast(float x) {
    return 1.f / (1.f + __expf(-x));
}

// ---------------------------------------------------------------------------
// C[m,n] = sum_k A[m,k] * B[n,k] + bias[n]   (B rows have leading dim Bld)
// A: fp32 or bf16, row-major M x K. M%128==0, N%128==0, K%32==0.
// Tile 128x128, BK=32, 4 waves, each wave 4x4 frags of 16x16x32 bf16 MFMA.
// ---------------------------------------------------------------------------
template <bool A_BF16>
__global__ __launch_bounds__(256, 2)
void gemm_bt(const void* __restrict__ Av, const float* __restrict__ Bm,
             const float* __restrict__ bias, float* __restrict__ C,
             int M, int N, int K, int Bld)
{
    __shared__ unsigned short As[128 * 32];
    __shared__ unsigned short Bs[128 * 32];

    const int m0 = blockIdx.x * 128;
    const int n0 = blockIdx.y * 128;
    const int tid  = threadIdx.x;
    const int lane = tid & 63;
    const int wave = tid >> 6;
    const int wm   = (wave & 1) * 64;
    const int wn   = (wave >> 1) * 64;
    const int quad = lane >> 4;   // 0..3
    const int l16  = lane & 15;

    f32x4 acc[4][4];
#pragma unroll
    for (int i = 0; i < 4; i++)
#pragma unroll
        for (int j = 0; j < 4; j++) acc[i][j] = (f32x4){0.f, 0.f, 0.f, 0.f};

    const int r0 = tid >> 2;  // 0..63 (row group)
    const int q4 = tid & 3;   // 0..3  (k sub-chunk of 8)

    for (int k0 = 0; k0 < K; k0 += 32) {
        __syncthreads();
#pragma unroll
        for (int rr = 0; rr < 2; rr++) {
            const int row = r0 + rr * 64;
            if (A_BF16) {
                const unsigned short* A16 = (const unsigned short*)Av;
                const uint4 v = *(const uint4*)(A16 + (size_t)(m0 + row) * K + k0 + q4 * 8);
                *(uint4*)(&As[row * 32 + q4 * 8]) = v;
            } else {
                const float* A32 = (const float*)Av;
                const float4 s0 = *(const float4*)(A32 + (size_t)(m0 + row) * K + k0 + q4 * 8);
                const float4 s1 = *(const float4*)(A32 + (size_t)(m0 + row) * K + k0 + q4 * 8 + 4);
                unsigned short tmp[8] = {f2bf(s0.x), f2bf(s0.y), f2bf(s0.z), f2bf(s0.w),
                                         f2bf(s1.x), f2bf(s1.y), f2bf(s1.z), f2bf(s1.w)};
                *(uint4*)(&As[row * 32 + q4 * 8]) = *(uint4*)tmp;
            }
            const float4 t0 = *(const float4*)(Bm + (size_t)(n0 + row) * Bld + k0 + q4 * 8);
            const float4 t1 = *(const float4*)(Bm + (size_t)(n0 + row) * Bld + k0 + q4 * 8 + 4);
            unsigned short tb[8] = {f2bf(t0.x), f2bf(t0.y), f2bf(t0.z), f2bf(t0.w),
                                    f2bf(t1.x), f2bf(t1.y), f2bf(t1.z), f2bf(t1.w)};
            *(uint4*)(&Bs[row * 32 + q4 * 8]) = *(uint4*)tb;
        }
        __syncthreads();

        bf16x8 af[4], bfr[4];
#pragma unroll
        for (int i = 0; i < 4; i++)
            af[i] = *(const bf16x8*)(&As[(wm + 16 * i + l16) * 32 + quad * 8]);
#pragma unroll
        for (int j = 0; j < 4; j++)
            bfr[j] = *(const bf16x8*)(&Bs[(wn + 16 * j + l16) * 32 + quad * 8]);
#pragma unroll
        for (int i = 0; i < 4; i++)
#pragma unroll
            for (int j = 0; j < 4; j++)
                acc[i][j] = __builtin_amdgcn_mfma_f32_16x16x32_bf16(af[i], bfr[j], acc[i][j], 0, 0, 0);
    }

#pragma unroll
    for (int i = 0; i < 4; i++)
#pragma unroll
        for (int j = 0; j < 4; j++)
#pragma unroll
            for (int r = 0; r < 4; r++) {
                const int m = m0 + wm + 16 * i + quad * 4 + r;
                const int n = n0 + wn + 16 * j + l16;
                C[(size_t)m * N + n] = acc[i][j][r] + bias[n];
            }
}

// ---------------------------------------------------------------------------
// M-loop variant: grid.x = N-tile; block iterates over ALL M-tiles.
// B-tile fetched from fabric ONCE per block (fetch ~N*K*4 bytes total);
// A re-read per m-tile from L2 (A is tiny + L2-resident).
// ---------------------------------------------------------------------------
template <bool A_BF16>
__global__ __launch_bounds__(256, 2)
void gemm_bt_ml(const void* __restrict__ Av, const float* __restrict__ Bm,
                const float* __restrict__ bias, float* __restrict__ C,
                int M, int N, int K, int Bld)
{
    __shared__ unsigned short As[128 * 32];
    __shared__ unsigned short Bs[128 * 32];

    const int n0 = blockIdx.x * 128;
    const int tid  = threadIdx.x;
    const int lane = tid & 63;
    const int wave = tid >> 6;
    const int wm   = (wave & 1) * 64;
    const int wn   = (wave >> 1) * 64;
    const int quad = lane >> 4;   // 0..3
    const int l16  = lane & 15;
    const int r0 = tid >> 2;  // 0..63 (row group)
    const int q4 = tid & 3;   // 0..3  (k sub-chunk of 8)

    for (int m0 = 0; m0 < M; m0 += 128) {
        f32x4 acc[4][4];
#pragma unroll
        for (int i = 0; i < 4; i++)
#pragma unroll
            for (int j = 0; j < 4; j++) acc[i][j] = (f32x4){0.f, 0.f, 0.f, 0.f};

        for (int k0 = 0; k0 < K; k0 += 32) {
            __syncthreads();
#pragma unroll
            for (int rr = 0; rr < 2; rr++) {
                const int row = r0 + rr * 64;
                if (A_BF16) {
                    const unsigned short* A16 = (const unsigned short*)Av;
                    const uint4 v = *(const uint4*)(A16 + (size_t)(m0 + row) * K + k0 + q4 * 8);
                    *(uint4*)(&As[row * 32 + q4 * 8]) = v;
                } else {
                    const float* A32 = (const float*)Av;
                    const float4 s0 = *(const float4*)(A32 + (size_t)(m0 + row) * K + k0 + q4 * 8);
                    const float4 s1 = *(const float4*)(A32 + (size_t)(m0 + row) * K + k0 + q4 * 8 + 4);
                    unsigned short tmp[8] = {f2bf(s0.x), f2bf(s0.y), f2bf(s0.z), f2bf(s0.w),
                                             f2bf(s1.x), f2bf(s1.y), f2bf(s1.z), f2bf(s1.w)};
                    *(uint4*)(&As[row * 32 + q4 * 8]) = *(uint4*)tmp;
                }
                const float4 t0 = *(const float4*)(Bm + (size_t)(n0 + row) * Bld + k0 + q4 * 8);
                const float4 t1 = *(const float4*)(Bm + (size_t)(n0 + row) * Bld + k0 + q4 * 8 + 4);
                unsigned short tb[8] = {f2bf(t0.x), f2bf(t0.y), f2bf(t0.z), f2bf(t0.w),
                                        f2bf(t1.x), f2bf(t1.y), f2bf(t1.z), f2bf(t1.w)};
                *(uint4*)(&Bs[row * 32 + q4 * 8]) = *(uint4*)tb;
            }
            __syncthreads();

            bf16x8 af[4], bfr[4];
#pragma unroll
            for (int i = 0; i < 4; i++)
                af[i] = *(const bf16x8*)(&As[(wm + 16 * i + l16) * 32 + quad * 8]);
#pragma unroll
            for (int j = 0; j < 4; j++)
                bfr[j] = *(const bf16x8*)(&Bs[(wn + 16 * j + l16) * 32 + quad * 8]);
#pragma unroll
            for (int i = 0; i < 4; i++)
#pragma unroll
                for (int j = 0; j < 4; j++)
                    acc[i][j] = __builtin_amdgcn_mfma_f32_16x16x32_bf16(af[i], bfr[j], acc[i][j], 0, 0, 0);
        }

#pragma unroll
        for (int i = 0; i < 4; i++)
#pragma unroll
            for (int j = 0; j < 4; j++)
#pragma unroll
                for (int r = 0; r < 4; r++) {
                    const int m = m0 + wm + 16 * i + quad * 4 + r;
                    const int n = n0 + wn + 16 * j + l16;
                    C[(size_t)m * N + n] = acc[i][j][r] + bias[n];
                }
    }
}

// ---------------------------------------------------------------------------
// h0 split-K partials: thread = (b, j, c) c in 0..3, K-chunk 256 of K=1024.
// ---------------------------------------------------------------------------
__global__ void k_h0part(const float* __restrict__ ehid, const float* __restrict__ Wh,
                         float* __restrict__ h0p)
{
    const int o = blockIdx.x * 256 + threadIdx.x;  // 65536
    const int b = o & 31, j = (o >> 5) & 511, c = o >> 14;
    const float* x = ehid + b * 1024 + c * 256;
    const float* w = Wh + (size_t)j * 1024 + c * 256;
    float s = 0.f;
#pragma unroll 8
    for (int k = 0; k < 256; k += 4)
        s += dot4(*(const float4*)(x + k), *(const float4*)(w + k));
    h0p[c * 16384 + b * 512 + j] = s;
}

__global__ void k_h0fin(const float* __restrict__ h0p, const float* __restrict__ bh,
                        float* __restrict__ h)
{
    const int o = blockIdx.x * 256 + threadIdx.x;  // 16384
    h[o] = bh[o & 511] + h0p[o] + h0p[16384 + o] + h0p[32768 + o] + h0p[49152 + o];
}

// ---------------------------------------------------------------------------
// Gather teacher-forced embedding rows: Xemb[b*T+t, :] = emb[tok(b,t), :]
// ---------------------------------------------------------------------------
__global__ void k_gather(const float* __restrict__ emb, const int* __restrict__ tgt,
                         float* __restrict__ Xemb)
{
    const int o = blockIdx.x * 256 + threadIdx.x;  // 131072
    const int r = o >> 7, k4 = (o & 127) * 4;
    const int b = r >> 5, t = r & 31;
    const int tok = t ? tgt[b * T_ + t - 1] : 0;
    *(float4*)(Xemb + (size_t)r * 512 + k4) = *(const float4*)(emb + (size_t)tok * 512 + k4);
}

// ---------------------------------------------------------------------------
// Persistent cooperative kernel for the whole T=32 scan.
// Grid: 128 blocks x 512 threads (1 block/CU, co-resident).
// Per step:
//   Phase AB: blocks 0..31  -> attention for batch b=bid (q, scores, softmax, ctx)
//             blocks 32..95 -> gh = h @ W_hh.T + b_hh  (split-K x2, LDS reduce)
//   grid.sync()
//   Phase C:  blocks 0..63  -> gx_ctx = ctx @ W_ih[:,512:].T (split-K x2)
//                              + GRU gates + h update + Hall write
//   grid.sync()
// Weight slices are disjoint per block (lane-shared rows), so each XCD's
// L2 working set (~3.7 MB) stays resident across steps.
// ---------------------------------------------------------------------------
__global__ __launch_bounds__(512)
void k_loop(float* __restrict__ h, float* __restrict__ ctx, float* __restrict__ ghs,
            const float* __restrict__ ua, const float* __restrict__ enc,
            const float* __restrict__ Wa_w, const float* __restrict__ Wa_b,
            const float* __restrict__ Va_w, const float* __restrict__ Va_b,
            const float* __restrict__ W_hh, const float* __restrict__ b_hh,
            const float* __restrict__ W_ih, const float* __restrict__ Gxe,
            unsigned short* __restrict__ Hall, float* __restrict__ attn_out,
            float* __restrict__ hf)
{
    cg::grid_group grid = cg::this_grid();
    const int bid = blockIdx.x;
    const int tid = threadIdx.x;

    __shared__ float hs[512];
    __shared__ float qs[512];
    __shared__ float parts[64][8];
    __shared__ float wsm[64];
    __shared__ float sred[3][512];

    for (int t = 0; t < T_; ++t) {
        // ---------------- Phase AB ----------------
        if (bid < 32) {
            // attention for b = bid
            const int b = bid;
            hs[tid] = h[b * 512 + tid];
            __syncthreads();
            // q[j] = dot(h[b], Wa_w[j]) + Wa_b[j], thread j = tid
            {
                const float* wr = Wa_w + (size_t)tid * 512;
                float acc = Wa_b[tid];
#pragma unroll 8
                for (int k = 0; k < 512; k += 4) {
                    const float4 h4 = *(const float4*)(hs + k);
                    acc += dot4(h4, *(const float4*)(wr + k));
                }
                qs[tid] = acc;
            }
            __syncthreads();
            // scores: s = tid>>3 (64), p = tid&7 (8 chunks of 64)
            {
                const int s = tid >> 3, p = tid & 7;
                const float* uar = ua + ((size_t)(b * 64 + s)) * 512 + p * 64;
                const float* vp  = Va_w + p * 64;
                const float* qpp = qs + p * 64;
                float acc = 0.f;
#pragma unroll 4
                for (int k = 0; k < 64; k += 4) {
                    const float4 u4 = *(const float4*)(uar + k);
                    const float4 v4 = *(const float4*)(vp + k);
                    const float4 q4 = *(const float4*)(qpp + k);
                    acc += v4.x * tanh_fast(q4.x + u4.x) + v4.y * tanh_fast(q4.y + u4.y)
                         + v4.z * tanh_fast(q4.z + u4.z) + v4.w * tanh_fast(q4.w + u4.w);
                }
                parts[s][p] = acc;
            }
            __syncthreads();
            if (tid < 64) {
                float sc = parts[tid][0] + parts[tid][1] + parts[tid][2] + parts[tid][3]
                         + parts[tid][4] + parts[tid][5] + parts[tid][6] + parts[tid][7]
                         + Va_b[0];
                float mx = sc;
                for (int off = 32; off; off >>= 1) mx = fmaxf(mx, __shfl_down(mx, off));
                mx = __shfl(mx, 0);
                const float e = __expf(sc - mx);
                float sum = e;
                for (int off = 32; off; off >>= 1) sum += __shfl_down(sum, off);
                sum = __shfl(sum, 0);
                const float w = e / sum;
                wsm[tid] = w;
                attn_out[((size_t)b * T_ + t) * 64 + tid] = w;
            }
            __syncthreads();
            // ctx: 1024 outputs, 2 per thread (float2), coalesced over enc
            {
                float2 a = {0.f, 0.f};
                const float* ebase = enc + (size_t)b * 65536 + tid * 2;
                for (int s2 = 0; s2 < 64; ++s2) {
                    const float w = wsm[s2];
                    const float2 e2 = *(const float2*)(ebase + (size_t)s2 * 1024);
                    a.x += w * e2.x; a.y += w * e2.y;
                }
                *(float2*)(ctx + b * 1024 + tid * 2) = a;
            }
        } else if (bid < 96) {
            // gh: block covers 8 j x 32 b, split-K x2 (K-half 256)
            const int gid = bid - 32;
            const int jl = tid & 7;
            const int b  = (tid >> 3) & 31;
            const int c  = tid >> 8;            // 0..1
            const int j  = gid * 8 + jl;        // 0..511
            const float* x  = h + b * 512 + c * 256;
            const float* w0 = W_hh + (size_t)j * 512 + c * 256;
            const float* w1 = w0 + 262144;      // 512*512
            const float* w2 = w1 + 262144;
            float s0 = 0.f, s1 = 0.f, s2 = 0.f;
#pragma unroll 4
            for (int k = 0; k < 256; k += 4) {
                const float4 xv = *(const float4*)(x + k);
                s0 += dot4(xv, *(const float4*)(w0 + k));
                s1 += dot4(xv, *(const float4*)(w1 + k));
                s2 += dot4(xv, *(const float4*)(w2 + k));
            }
            sred[0][tid] = s0; sred[1][tid] = s1; sred[2][tid] = s2;
            __syncthreads();
            if (tid < 256) {
                const int j2 = gid * 8 + (tid & 7);
                const int b2 = tid >> 3;
                const int o2 = j2 * 32 + b2;
                ghs[o2]         = sred[0][tid] + sred[0][tid + 256] + b_hh[j2];
                ghs[16384 + o2] = sred[1][tid] + sred[1][tid + 256] + b_hh[512 + j2];
                ghs[32768 + o2] = sred[2][tid] + sred[2][tid + 256] + b_hh[1024 + j2];
            }
        }
        grid.sync();
        // ---------------- Phase C ----------------
        if (bid < 64) {
            // gx_ctx + finalize: block covers 8 j x 32 b, split-K x2 (K-half 512)
            const int jl = tid & 7;
            const int b  = (tid >> 3) & 31;
            const int c  = tid >> 8;            // 0..1
            const int j  = bid * 8 + jl;        // 0..511
            const float* x  = ctx + b * 1024 + c * 512;
            const float* w0 = W_ih + (size_t)j * 1536 + 512 + c * 512;
            const float* w1 = w0 + 786432;      // 512*1536
            const float* w2 = w1 + 786432;
            float s0 = 0.f, s1 = 0.f, s2 = 0.f;
#pragma unroll 4
            for (int k = 0; k < 512; k += 4) {
                const float4 xv = *(const float4*)(x + k);
                s0 += dot4(xv, *(const float4*)(w0 + k));
                s1 += dot4(xv, *(const float4*)(w1 + k));
                s2 += dot4(xv, *(const float4*)(w2 + k));
            }
            sred[0][tid] = s0; sred[1][tid] = s1; sred[2][tid] = s2;
            __syncthreads();
            if (tid < 256) {
                const int j2 = bid * 8 + (tid & 7);
                const int b2 = tid >> 3;
                const int o2 = j2 * 32 + b2;
                const float g0 = sred[0][tid] + sred[0][tid + 256];
                const float g1 = sred[1][tid] + sred[1][tid + 256];
                const float g2 = sred[2][tid] + sred[2][tid + 256];
                const float* gxe = Gxe + ((size_t)(b2 * T_ + t)) * 1536;
                const float gx0 = gxe[j2] + g0;
                const float gx1 = gxe[512 + j2] + g1;
                const float gx2 = gxe[1024 + j2] + g2;
                const float gh0 = ghs[o2];
                const float gh1 = ghs[16384 + o2];
                const float gh2 = ghs[32768 + o2];
                const float r = sigmoid_fast(gx0 + gh0);
                const float z = sigmoid_fast(gx1 + gh1);
                const float n = tanh_fast(gx2 + r * gh2);
                const int ho = b2 * 512 + j2;
                const float hn = (1.f - z) * n + z * h[ho];
                h[ho] = hn;
                Hall[((size_t)b2 * T_ + t) * 512 + j2] = f2bf(hn);
                if (t == T_ - 1) hf[ho] = hn;
            }
        }
        grid.sync();
    }
}

// ---------------------------------------------------------------------------
// Fallback per-step kernels (used only if cooperative launch is unavailable)
// ---------------------------------------------------------------------------
__global__ void k_q(const float* __restrict__ h, const float* __restrict__ Wa_w,
                    float* __restrict__ qp)
{
    const int o = blockIdx.x * 256 + threadIdx.x;  // 65536
    const int b = o & 31, j = (o >> 5) & 511, c = o >> 14;
    const float* x = h + b * 512 + c * 128;
    const float* w = Wa_w + (size_t)j * 512 + c * 128;
    float s = 0.f;
#pragma unroll 8
    for (int k = 0; k < 128; k += 4)
        s += dot4(*(const float4*)(x + k), *(const float4*)(w + k));
    qp[c * 16384 + b * 512 + j] = s;
}

__global__ void k_attn(const float* __restrict__ qp, const float* __restrict__ Wa_b,
                       const float* __restrict__ ua, const float* __restrict__ Va_w,
                       const float* __restrict__ Va_b, const float* __restrict__ enc,
                       float* __restrict__ ctx, float* __restrict__ attn_out, int t)
{
    __shared__ float qs[512];
    __shared__ float parts[64][4];
    __shared__ float wsm[64];
    const int b = blockIdx.x;
    const int tid = threadIdx.x;

    for (int i = tid; i < 512; i += 256) {
        const int ix = b * 512 + i;
        qs[i] = qp[ix] + qp[16384 + ix] + qp[32768 + ix] + qp[49152 + ix] + Wa_b[i];
    }
    __syncthreads();

    const int s = tid >> 2, p = tid & 3;
    {
        const float* uar = ua + ((size_t)(b * 64 + s)) * 512 + p * 128;
        const float* vp = Va_w + p * 128;
        float acc = 0.f;
#pragma unroll 8
        for (int k = 0; k < 128; k += 4) {
            float4 u4 = *(const float4*)(uar + k);
            float4 v4 = *(const float4*)(vp + k);
            float4 q4 = *(const float4*)(&qs[p * 128 + k]);
            acc += v4.x * tanh_fast(q4.x + u4.x) + v4.y * tanh_fast(q4.y + u4.y)
                 + v4.z * tanh_fast(q4.z + u4.z) + v4.w * tanh_fast(q4.w + u4.w);
        }
        parts[s][p] = acc;
    }
    __syncthreads();

    if (tid < 64) {
        float sc = parts[tid][0] + parts[tid][1] + parts[tid][2] + parts[tid][3] + Va_b[0];
        float mx = sc;
        for (int off = 32; off; off >>= 1) mx = fmaxf(mx, __shfl_down(mx, off));
        mx = __shfl(mx, 0);
        float e = __expf(sc - mx);
        float sum = e;
        for (int off = 32; off; off >>= 1) sum += __shfl_down(sum, off);
        sum = __shfl(sum, 0);
        float w = e / sum;
        wsm[tid] = w;
        attn_out[((size_t)b * T_ + t) * 64 + tid] = w;
    }
    __syncthreads();

    {
        const int mm = tid * 4;
        float4 a = {0.f, 0.f, 0.f, 0.f};
        for (int s2 = 0; s2 < 64; s2++) {
            const float w = wsm[s2];
            const float4 e4 = *(const float4*)(enc + ((size_t)(b * 64 + s2)) * 1024 + mm);
            a.x += w * e4.x; a.y += w * e4.y; a.z += w * e4.z; a.w += w * e4.w;
        }
        *(float4*)(ctx + b * 1024 + mm) = a;
    }
}

__global__ void k_ggx(const float* __restrict__ h, const float* __restrict__ ctx,
                      const float* __restrict__ W_hh, const float* __restrict__ W_ih,
                      float* __restrict__ ghp, float* __restrict__ gxp)
{
    const int o = blockIdx.x * 256 + threadIdx.x;  // 196608
    if (o < 65536) {
        const int b = o & 31, j = (o >> 5) & 511, c = o >> 14;  // c 0..3
        const float* x  = h + b * 512 + c * 128;
        const float* w0 = W_hh + (size_t)j * 512 + c * 128;
        const float* w1 = w0 + 512 * 512;
        const float* w2 = w1 + 512 * 512;
        float s0 = 0.f, s1 = 0.f, s2 = 0.f;
#pragma unroll 8
        for (int k = 0; k < 128; k += 4) {
            const float4 xv = *(const float4*)(x + k);
            s0 += dot4(xv, *(const float4*)(w0 + k));
            s1 += dot4(xv, *(const float4*)(w1 + k));
            s2 += dot4(xv, *(const float4*)(w2 + k));
        }
        const int ix = b * 512 + j;
        ghp[(c * 3 + 0) * 16384 + ix] = s0;
        ghp[(c * 3 + 1) * 16384 + ix] = s1;
        ghp[(c * 3 + 2) * 16384 + ix] = s2;
    } else {
        const int oo = o - 65536;
        const int b = oo & 31, j = (oo >> 5) & 511, c = oo >> 14;  // c 0..7
        const float* x  = ctx + b * 1024 + c * 128;
        const float* w0 = W_ih + (size_t)j * 1536 + 512 + c * 128;
        const float* w1 = w0 + 512 * 1536;
        const float* w2 = w1 + 512 * 1536;
        float s0 = 0.f, s1 = 0.f, s2 = 0.f;
#pragma unroll 8
        for (int k = 0; k < 128; k += 4) {
            const float4 xv = *(const float4*)(x + k);
            s0 += dot4(xv, *(const float4*)(w0 + k));
            s1 += dot4(xv, *(const float4*)(w1 + k));
            s2 += dot4(xv, *(const float4*)(w2 + k));
        }
        const int ix = b * 512 + j;
        gxp[(c * 3 + 0) * 16384 + ix] = s0;
        gxp[(c * 3 + 1) * 16384 + ix] = s1;
        gxp[(c * 3 + 2) * 16384 + ix] = s2;
    }
}

__global__ void k_fin(const float* __restrict__ ghp, const float* __restrict__ gxp,
                      const float* __restrict__ Gxe, const float* __restrict__ b_hh,
                      float* __restrict__ h, unsigned short* __restrict__ Hall,
                      float* __restrict__ hfin, int t)
{
    const int o = blockIdx.x * 256 + threadIdx.x;  // 16384 (o == b*512+j)
    const int b = o >> 9, j = o & 511;
    float gh0 = b_hh[j], gh1 = b_hh[512 + j], gh2 = b_hh[1024 + j];
#pragma unroll
    for (int c = 0; c < 4; c++) {
        gh0 += ghp[(c * 3 + 0) * 16384 + o];
        gh1 += ghp[(c * 3 + 1) * 16384 + o];
        gh2 += ghp[(c * 3 + 2) * 16384 + o];
    }
    const float* gxe = Gxe + ((size_t)(b * T_ + t)) * 1536;
    float gx0 = gxe[j], gx1 = gxe[512 + j], gx2 = gxe[1024 + j];
#pragma unroll
    for (int c = 0; c < 8; c++) {
        gx0 += gxp[(c * 3 + 0) * 16384 + o];
        gx1 += gxp[(c * 3 + 1) * 16384 + o];
        gx2 += gxp[(c * 3 + 2) * 16384 + o];
    }
    const float r = sigmoid_fast(gx0 + gh0);
    const float z = sigmoid_fast(gx1 + gh1);
    const float n = tanh_fast(gx2 + r * gh2);
    const float hn = (1.f - z) * n + z * h[o];
    h[o] = hn;
    Hall[((size_t)b * T_ + t) * 512 + j] = f2bf(hn);
    if (hfin) hfin[o] = hn;
}

// ---------------------------------------------------------------------------
// Online log_softmax over V=32000 per row, in place. One block per row.
// ---------------------------------------------------------------------------
__global__ void k_logsoftmax(float* __restrict__ logits)
{
    __shared__ float rm[4], rs[4];
    const int row = blockIdx.x;
    float* p = logits + (size_t)row * V_;
    const int tid = threadIdx.x;

    float m = -1e30f, s = 0.f;
    for (int i = tid * 4; i < V_; i += 1024) {
        const float4 x = *(const float4*)(p + i);
        const float m4 = fmaxf(fmaxf(x.x, x.y), fmaxf(x.z, x.w));
        const float mn = fmaxf(m, m4);
        s = s * __expf(m - mn) + __expf(x.x - mn) + __expf(x.y - mn)
          + __expf(x.z - mn) + __expf(x.w - mn);
        m = mn;
    }
    for (int off = 32; off; off >>= 1) {
        const float m2 = __shfl_down(m, off), s2 = __shfl_down(s, off);
        const float mn = fmaxf(m, m2);
        s = s * __expf(m - mn) + s2 * __expf(m2 - mn);
        m = mn;
    }
    if ((tid & 63) == 0) { rm[tid >> 6] = m; rs[tid >> 6] = s; }
    __syncthreads();
    const float M = fmaxf(fmaxf(rm[0], rm[1]), fmaxf(rm[2], rm[3]));
    const float S = rs[0] * __expf(rm[0] - M) + rs[1] * __expf(rm[1] - M)
                  + rs[2] * __expf(rm[2] - M) + rs[3] * __expf(rm[3] - M);
    const float lse = M + __logf(S);

    for (int i = tid * 4; i < V_; i += 1024) {
        float4 x = *(const float4*)(p + i);
        x.x -= lse; x.y -= lse; x.z -= lse; x.w -= lse;
        *(float4*)(p + i) = x;
    }
}

// ---------------------------------------------------------------------------
extern "C" void kernel_launch(void* const* d_in, const int* in_sizes, int n_in,
                              void* d_out, int out_size, void* d_ws, size_t ws_size,
                              hipStream_t stream)
{
    const float* enc   = (const float*)d_in[0];   // [B,S,2H]
    const float* ehid  = (const float*)d_in[1];   // [1,B,2H]
    const int*   tgt   = (const int*)d_in[2];     // [B,T]
    const float* emb   = (const float*)d_in[3];   // [V,H]
    const float* Wa_w  = (const float*)d_in[4];   // [H,H]
    const float* Wa_b  = (const float*)d_in[5];
    const float* Ua_w  = (const float*)d_in[6];   // [H,2H]
    const float* Ua_b  = (const float*)d_in[7];
    const float* Va_w  = (const float*)d_in[8];   // [1,H]
    const float* Va_b  = (const float*)d_in[9];   // [1]
    const float* W_ih  = (const float*)d_in[10];  // [3H,3H]
    const float* b_ih  = (const float*)d_in[11];
    const float* W_hh  = (const float*)d_in[12];  // [3H,H]
    const float* b_hh  = (const float*)d_in[13];
    const float* Wh    = (const float*)d_in[14];  // [H,2H]
    const float* bh    = (const float*)d_in[15];
    const float* out_w = (const float*)d_in[16];  // [V,H]
    const float* out_b = (const float*)d_in[17];  // [V]

    float* outp = (float*)d_out;
    float* lp   = outp;                 // [B,T,V] = 32,768,000 floats
    float* hf   = outp + 32768000;      // [1,B,H]
    float* attn = outp + 32784384;      // [B,T,S]

    // Transient scratch inside the lp region (dead before the logits GEMM
    // overwrites all of lp):
    float* Gxe  = lp;                   // 1,572,864  [B*T, 3H] emb-part + b_ih
    float* Xemb = lp + 1572864;         //   524,288  [B*T, H]
    float* ghs  = lp + 2097152;         //    49,152  3 x [B*H] (coop loop)
    float* qp   = lp + 2097152;         //    65,536  4 x [B*H] (fallback only)
    float* ghp  = lp + 2162688;         //   196,608  12 x [B*H] (fallback only)
    float* gxp  = lp + 2359296;         //   393,216  24 x [B*H] (fallback only)
    float* h0p  = gxp;                  // setup-only alias (4 x 16384)

    // Persistent ws (~5.4 MB)
    float* ws  = (float*)d_ws;
    float* h   = ws;                    // 16,384
    float* ctx = ws + 16384;            // 32,768
    float* ua  = ws + 49152;            // 1,048,576  [B*S, H]
    unsigned short* Hall = (unsigned short*)(ws + 1097728);  // [B*T, H] bf16

    // ---- setup ----
    k_h0part<<<256, 256, 0, stream>>>(ehid, Wh, h0p);
    k_h0fin<<<64, 256, 0, stream>>>(h0p, bh, h);
    k_gather<<<512, 256, 0, stream>>>(emb, tgt, Xemb);
    gemm_bt<false><<<dim3(16, 4), 256, 0, stream>>>(enc, Ua_w, Ua_b, ua,
                                                    2048, 512, 1024, 1024);
    gemm_bt<false><<<dim3(8, 12), 256, 0, stream>>>(Xemb, W_ih, b_ih, Gxe,
                                                    1024, 1536, 512, 1536);

    // ---- sequential scan: one persistent cooperative kernel ----
    {
        float* h_p = h; float* ctx_p = ctx; float* ghs_p = ghs;
        const float* ua_p = ua; const float* enc_p = enc;
        const float* Waw_p = Wa_w; const float* Wab_p = Wa_b;
        const float* Vaw_p = Va_w; const float* Vab_p = Va_b;
        const float* Whh_p = W_hh; const float* bhh_p = b_hh;
        const float* Wih_p = W_ih; const float* Gxe_p = Gxe;
        unsigned short* Hall_p = Hall; float* attn_p = attn; float* hf_p = hf;
        void* kargs[] = {&h_p, &ctx_p, &ghs_p, &ua_p, &enc_p, &Waw_p, &Wab_p,
                         &Vaw_p, &Vab_p, &Whh_p, &bhh_p, &Wih_p, &Gxe_p,
                         &Hall_p, &attn_p, &hf_p};
        hipError_t err = hipLaunchCooperativeKernel(
            (const void*)k_loop, dim3(128), dim3(512), kargs, 0, stream);
        if (err != hipSuccess) {
            // Fallback: original 4-kernel per-step loop
            for (int t = 0; t < T_; t++) {
                k_q<<<256, 256, 0, stream>>>(h, Wa_w, qp);
                k_attn<<<32, 256, 0, stream>>>(qp, Wa_b, ua, Va_w, Va_b, enc, ctx, attn, t);
                k_ggx<<<768, 256, 0, stream>>>(h, ctx, W_hh, W_ih, ghp, gxp);
                k_fin<<<64, 256, 0, stream>>>(ghp, gxp, Gxe, b_hh, h, Hall,
                                              (t == T_ - 1) ? hf : nullptr, t);
            }
        }
    }

    // ---- logits + log_softmax ----
    gemm_bt_ml<true><<<250, 256, 0, stream>>>(Hall, out_w, out_b, lp,
                                              1024, V_, 512, 512);
    k_logsoftmax<<<1024, 256, 0, stream>>>(lp);
}

// Round 5
// 2734.623 us; speedup vs baseline: 2.1380x; 2.1380x over previous
//
#include <hip/hip_runtime.h>
#include <hip/hip_bf16.h>

// Problem dims (fixed)
#define B_ 32
#define S_ 64
#define H_ 512
#define T_ 32
#define V_ 32000

typedef __attribute__((ext_vector_type(8))) short bf16x8;
typedef __attribute__((ext_vector_type(4))) float f32x4;

static __device__ __forceinline__ unsigned short f2bf(float f) {
    unsigned int u = __float_as_uint(f);
    u += 0x7FFF + ((u >> 16) & 1);   // RNE
    return (unsigned short)(u >> 16);
}
static __device__ __forceinline__ float dot4(float4 a, float4 b) {
    return a.x * b.x + a.y * b.y + a.z * b.z + a.w * b.w;
}
static __device__ __forceinline__ float tanh_fast(float x) {
    x = fminf(fmaxf(x, -15.f), 15.f);
    float e = __expf(2.f * x);
    return (e - 1.f) / (e + 1.f);
}
static __device__ __forceinline__ float sigmoid_fast(float x) {
    return 1.f / (1.f + __expf(-x));
}

// ---------------------------------------------------------------------------
// C[m,n] = sum_k A[m,k] * B[n,k] + bias[n]   (B rows have leading dim Bld)
// Tile 128x128, BK=32, 4 waves, each wave 4x4 frags of 16x16x32 bf16 MFMA.
// (verified r0)
// ---------------------------------------------------------------------------
template <bool A_BF16>
__global__ __launch_bounds__(256, 2)
void gemm_bt(const void* __restrict__ Av, const float* __restrict__ Bm,
             const float* __restrict__ bias, float* __restrict__ C,
             int M, int N, int K, int Bld)
{
    __shared__ unsigned short As[128 * 32];
    __shared__ unsigned short Bs[128 * 32];

    const int m0 = blockIdx.x * 128;
    const int n0 = blockIdx.y * 128;
    const int tid  = threadIdx.x;
    const int lane = tid & 63;
    const int wave = tid >> 6;
    const int wm   = (wave & 1) * 64;
    const int wn   = (wave >> 1) * 64;
    const int quad = lane >> 4;   // 0..3
    const int l16  = lane & 15;

    f32x4 acc[4][4];
#pragma unroll
    for (int i = 0; i < 4; i++)
#pragma unroll
        for (int j = 0; j < 4; j++) acc[i][j] = (f32x4){0.f, 0.f, 0.f, 0.f};

    const int r0 = tid >> 2;  // 0..63 (row group)
    const int q4 = tid & 3;   // 0..3  (k sub-chunk of 8)

    for (int k0 = 0; k0 < K; k0 += 32) {
        __syncthreads();
#pragma unroll
        for (int rr = 0; rr < 2; rr++) {
            const int row = r0 + rr * 64;
            if (A_BF16) {
                const unsigned short* A16 = (const unsigned short*)Av;
                const uint4 v = *(const uint4*)(A16 + (size_t)(m0 + row) * K + k0 + q4 * 8);
                *(uint4*)(&As[row * 32 + q4 * 8]) = v;
            } else {
                const float* A32 = (const float*)Av;
                const float4 s0 = *(const float4*)(A32 + (size_t)(m0 + row) * K + k0 + q4 * 8);
                const float4 s1 = *(const float4*)(A32 + (size_t)(m0 + row) * K + k0 + q4 * 8 + 4);
                unsigned short tmp[8] = {f2bf(s0.x), f2bf(s0.y), f2bf(s0.z), f2bf(s0.w),
                                         f2bf(s1.x), f2bf(s1.y), f2bf(s1.z), f2bf(s1.w)};
                *(uint4*)(&As[row * 32 + q4 * 8]) = *(uint4*)tmp;
            }
            const float4 t0 = *(const float4*)(Bm + (size_t)(n0 + row) * Bld + k0 + q4 * 8);
            const float4 t1 = *(const float4*)(Bm + (size_t)(n0 + row) * Bld + k0 + q4 * 8 + 4);
            unsigned short tb[8] = {f2bf(t0.x), f2bf(t0.y), f2bf(t0.z), f2bf(t0.w),
                                    f2bf(t1.x), f2bf(t1.y), f2bf(t1.z), f2bf(t1.w)};
            *(uint4*)(&Bs[row * 32 + q4 * 8]) = *(uint4*)tb;
        }
        __syncthreads();

        bf16x8 af[4], bfr[4];
#pragma unroll
        for (int i = 0; i < 4; i++)
            af[i] = *(const bf16x8*)(&As[(wm + 16 * i + l16) * 32 + quad * 8]);
#pragma unroll
        for (int j = 0; j < 4; j++)
            bfr[j] = *(const bf16x8*)(&Bs[(wn + 16 * j + l16) * 32 + quad * 8]);
#pragma unroll
        for (int i = 0; i < 4; i++)
#pragma unroll
            for (int j = 0; j < 4; j++)
                acc[i][j] = __builtin_amdgcn_mfma_f32_16x16x32_bf16(af[i], bfr[j], acc[i][j], 0, 0, 0);
    }

#pragma unroll
    for (int i = 0; i < 4; i++)
#pragma unroll
        for (int j = 0; j < 4; j++)
#pragma unroll
            for (int r = 0; r < 4; r++) {
                const int m = m0 + wm + 16 * i + quad * 4 + r;
                const int n = n0 + wn + 16 * j + l16;
                C[(size_t)m * N + n] = acc[i][j][r] + bias[n];
            }
}

// M-loop variant: grid.x = N-tile; block iterates over ALL M-tiles (B-tile
// fetched once per block; A tiny + L2-resident). Ran + passed in r1.
template <bool A_BF16>
__global__ __launch_bounds__(256, 2)
void gemm_bt_ml(const void* __restrict__ Av, const float* __restrict__ Bm,
                const float* __restrict__ bias, float* __restrict__ C,
                int M, int N, int K, int Bld)
{
    __shared__ unsigned short As[128 * 32];
    __shared__ unsigned short Bs[128 * 32];

    const int n0 = blockIdx.x * 128;
    const int tid  = threadIdx.x;
    const int lane = tid & 63;
    const int wave = tid >> 6;
    const int wm   = (wave & 1) * 64;
    const int wn   = (wave >> 1) * 64;
    const int quad = lane >> 4;   // 0..3
    const int l16  = lane & 15;
    const int r0 = tid >> 2;  // 0..63 (row group)
    const int q4 = tid & 3;   // 0..3  (k sub-chunk of 8)

    for (int m0 = 0; m0 < M; m0 += 128) {
        f32x4 acc[4][4];
#pragma unroll
        for (int i = 0; i < 4; i++)
#pragma unroll
            for (int j = 0; j < 4; j++) acc[i][j] = (f32x4){0.f, 0.f, 0.f, 0.f};

        for (int k0 = 0; k0 < K; k0 += 32) {
            __syncthreads();
#pragma unroll
            for (int rr = 0; rr < 2; rr++) {
                const int row = r0 + rr * 64;
                if (A_BF16) {
                    const unsigned short* A16 = (const unsigned short*)Av;
                    const uint4 v = *(const uint4*)(A16 + (size_t)(m0 + row) * K + k0 + q4 * 8);
                    *(uint4*)(&As[row * 32 + q4 * 8]) = v;
                } else {
                    const float* A32 = (const float*)Av;
                    const float4 s0 = *(const float4*)(A32 + (size_t)(m0 + row) * K + k0 + q4 * 8);
                    const float4 s1 = *(const float4*)(A32 + (size_t)(m0 + row) * K + k0 + q4 * 8 + 4);
                    unsigned short tmp[8] = {f2bf(s0.x), f2bf(s0.y), f2bf(s0.z), f2bf(s0.w),
                                             f2bf(s1.x), f2bf(s1.y), f2bf(s1.z), f2bf(s1.w)};
                    *(uint4*)(&As[row * 32 + q4 * 8]) = *(uint4*)tmp;
                }
                const float4 t0 = *(const float4*)(Bm + (size_t)(n0 + row) * Bld + k0 + q4 * 8);
                const float4 t1 = *(const float4*)(Bm + (size_t)(n0 + row) * Bld + k0 + q4 * 8 + 4);
                unsigned short tb[8] = {f2bf(t0.x), f2bf(t0.y), f2bf(t0.z), f2bf(t0.w),
                                        f2bf(t1.x), f2bf(t1.y), f2bf(t1.z), f2bf(t1.w)};
                *(uint4*)(&Bs[row * 32 + q4 * 8]) = *(uint4*)tb;
            }
            __syncthreads();

            bf16x8 af[4], bfr[4];
#pragma unroll
            for (int i = 0; i < 4; i++)
                af[i] = *(const bf16x8*)(&As[(wm + 16 * i + l16) * 32 + quad * 8]);
#pragma unroll
            for (int j = 0; j < 4; j++)
                bfr[j] = *(const bf16x8*)(&Bs[(wn + 16 * j + l16) * 32 + quad * 8]);
#pragma unroll
            for (int i = 0; i < 4; i++)
#pragma unroll
                for (int j = 0; j < 4; j++)
                    acc[i][j] = __builtin_amdgcn_mfma_f32_16x16x32_bf16(af[i], bfr[j], acc[i][j], 0, 0, 0);
        }

#pragma unroll
        for (int i = 0; i < 4; i++)
#pragma unroll
            for (int j = 0; j < 4; j++)
#pragma unroll
                for (int r = 0; r < 4; r++) {
                    const int m = m0 + wm + 16 * i + quad * 4 + r;
                    const int n = n0 + wn + 16 * j + l16;
                    C[(size_t)m * N + n] = acc[i][j][r] + bias[n];
                }
    }
}

// --------------------------------------------------------------------------- 
// setup kernels (verbatim r0, all 256-thread)
// ---------------------------------------------------------------------------
__global__ void k_h0part(const float* __restrict__ ehid, const float* __restrict__ Wh,
                         float* __restrict__ h0p)
{
    const int o = blockIdx.x * 256 + threadIdx.x;  // 65536
    const int b = o & 31, j = (o >> 5) & 511, c = o >> 14;
    const float* x = ehid + b * 1024 + c * 256;
    const float* w = Wh + (size_t)j * 1024 + c * 256;
    float s = 0.f;
#pragma unroll 8
    for (int k = 0; k < 256; k += 4)
        s += dot4(*(const float4*)(x + k), *(const float4*)(w + k));
    h0p[c * 16384 + b * 512 + j] = s;
}

__global__ void k_h0fin(const float* __restrict__ h0p, const float* __restrict__ bh,
                        float* __restrict__ h)
{
    const int o = blockIdx.x * 256 + threadIdx.x;  // 16384
    h[o] = bh[o & 511] + h0p[o] + h0p[16384 + o] + h0p[32768 + o] + h0p[49152 + o];
}

__global__ void k_gather(const float* __restrict__ emb, const int* __restrict__ tgt,
                         float* __restrict__ Xemb)
{
    const int o = blockIdx.x * 256 + threadIdx.x;  // 131072
    const int r = o >> 7, k4 = (o & 127) * 4;
    const int b = r >> 5, t = r & 31;
    const int tok = t ? tgt[b * T_ + t - 1] : 0;
    *(float4*)(Xemb + (size_t)r * 512 + k4) = *(const float4*)(emb + (size_t)tok * 512 + k4);
}

// ---------------------------------------------------------------------------
// Scan launch 1: 288 blocks x 256 threads.
//  blocks 0..31 : attention for batch b = bid. q computed in-block
//                 (2 outputs/thread, full K=512); then the VERBATIM r0
//                 k_attn score/softmax/ctx body.
//  blocks 32..287: gh partials, VERBATIM r0 k_ggx gh-half layout
//                 (o = (bid-32)*256+tid in 0..65535).
// ---------------------------------------------------------------------------
__global__ __launch_bounds__(256)
void k_attn_gh(const float* __restrict__ h, const float* __restrict__ Wa_w,
               const float* __restrict__ Wa_b, const float* __restrict__ ua,
               const float* __restrict__ Va_w, const float* __restrict__ Va_b,
               const float* __restrict__ enc, const float* __restrict__ W_hh,
               float* __restrict__ ctx, float* __restrict__ ghp,
               float* __restrict__ attn_out, int t)
{
    __shared__ float hs[512];
    __shared__ float qs[512];
    __shared__ float parts[64][4];
    __shared__ float wsm[64];

    const int bid = blockIdx.x;
    const int tid = threadIdx.x;

    if (bid < 32) {
        const int b = bid;
        hs[tid]       = h[b * 512 + tid];
        hs[tid + 256] = h[b * 512 + tid + 256];
        __syncthreads();
        // q[j] = h[b]·Wa_w[j] + Wa_b[j]; 2 outputs per thread
#pragma unroll
        for (int jj = 0; jj < 2; jj++) {
            const int j = tid + jj * 256;
            const float* wr = Wa_w + (size_t)j * 512;
            float acc = Wa_b[j];
#pragma unroll 8
            for (int k = 0; k < 512; k += 4)
                acc += dot4(*(const float4*)(hs + k), *(const float4*)(wr + k));
            qs[j] = acc;
        }
        __syncthreads();
        // ---- r0 k_attn body (verbatim) ----
        const int s = tid >> 2, p = tid & 3;
        {
            const float* uar = ua + ((size_t)(b * 64 + s)) * 512 + p * 128;
            const float* vp = Va_w + p * 128;
            float acc = 0.f;
#pragma unroll 8
            for (int k = 0; k < 128; k += 4) {
                float4 u4 = *(const float4*)(uar + k);
                float4 v4 = *(const float4*)(vp + k);
                float4 q4 = *(const float4*)(&qs[p * 128 + k]);
                acc += v4.x * tanh_fast(q4.x + u4.x) + v4.y * tanh_fast(q4.y + u4.y)
                     + v4.z * tanh_fast(q4.z + u4.z) + v4.w * tanh_fast(q4.w + u4.w);
            }
            parts[s][p] = acc;
        }
        __syncthreads();
        if (tid < 64) {
            float sc = parts[tid][0] + parts[tid][1] + parts[tid][2] + parts[tid][3] + Va_b[0];
            float mx = sc;
            for (int off = 32; off; off >>= 1) mx = fmaxf(mx, __shfl_down(mx, off));
            mx = __shfl(mx, 0);
            float e = __expf(sc - mx);
            float sum = e;
            for (int off = 32; off; off >>= 1) sum += __shfl_down(sum, off);
            sum = __shfl(sum, 0);
            float w = e / sum;
            wsm[tid] = w;
            attn_out[((size_t)b * T_ + t) * 64 + tid] = w;
        }
        __syncthreads();
        {
            const int mm = tid * 4;
            float4 a = {0.f, 0.f, 0.f, 0.f};
            for (int s2 = 0; s2 < 64; s2++) {
                const float w = wsm[s2];
                const float4 e4 = *(const float4*)(enc + ((size_t)(b * 64 + s2)) * 1024 + mm);
                a.x += w * e4.x; a.y += w * e4.y; a.z += w * e4.z; a.w += w * e4.w;
            }
            *(float4*)(ctx + b * 1024 + mm) = a;
        }
    } else {
        // ---- r0 k_ggx gh-half (verbatim layout) ----
        const int o = (bid - 32) * 256 + tid;                 // 0..65535
        const int b = o & 31, j = (o >> 5) & 511, c = o >> 14;  // c 0..3
        const float* x  = h + b * 512 + c * 128;
        const float* w0 = W_hh + (size_t)j * 512 + c * 128;
        const float* w1 = w0 + 512 * 512;
        const float* w2 = w1 + 512 * 512;
        float s0 = 0.f, s1 = 0.f, s2 = 0.f;
#pragma unroll 8
        for (int k = 0; k < 128; k += 4) {
            const float4 xv = *(const float4*)(x + k);
            s0 += dot4(xv, *(const float4*)(w0 + k));
            s1 += dot4(xv, *(const float4*)(w1 + k));
            s2 += dot4(xv, *(const float4*)(w2 + k));
        }
        const int ix = b * 512 + j;
        ghp[(c * 3 + 0) * 16384 + ix] = s0;
        ghp[(c * 3 + 1) * 16384 + ix] = s1;
        ghp[(c * 3 + 2) * 16384 + ix] = s2;
    }
}

// ---------------------------------------------------------------------------
// Scan launch 2: 512 blocks x 256 threads. Block = one j (0..511).
// Threads (b = tid&31, c = tid>>5, c 0..7): gx partials over ctx K-chunk 128
// (r0 k_ggx gx-half math), LDS reduce over c, then threads 0..31 apply the
// VERBATIM r0 k_fin gate math for (b, j).
// ---------------------------------------------------------------------------
__global__ __launch_bounds__(256)
void k_gx_fin(const float* __restrict__ ctx, const float* __restrict__ W_ih,
              const float* __restrict__ ghp, const float* __restrict__ Gxe,
              const float* __restrict__ b_hh, float* __restrict__ h,
              unsigned short* __restrict__ Hall, float* __restrict__ hf, int t)
{
    __shared__ float sred[3][256];
    const int tid = threadIdx.x;
    const int j = blockIdx.x;                 // 0..511
    const int b = tid & 31, c = tid >> 5;     // c 0..7 (K-chunk 128 of 1024)

    const float* y  = ctx + b * 1024 + c * 128;
    const float* u0 = W_ih + (size_t)j * 1536 + 512 + c * 128;
    const float* u1 = u0 + 512 * 1536;
    const float* u2 = u1 + 512 * 1536;
    float s0 = 0.f, s1 = 0.f, s2 = 0.f;
#pragma unroll 8
    for (int k = 0; k < 128; k += 4) {
        const float4 yv = *(const float4*)(y + k);
        s0 += dot4(yv, *(const float4*)(u0 + k));
        s1 += dot4(yv, *(const float4*)(u1 + k));
        s2 += dot4(yv, *(const float4*)(u2 + k));
    }
    sred[0][tid] = s0; sred[1][tid] = s1; sred[2][tid] = s2;
    __syncthreads();

    if (tid < 32) {
        const int b2 = tid;
        float gx0 = 0.f, gx1 = 0.f, gx2 = 0.f;
#pragma unroll
        for (int c2 = 0; c2 < 8; c2++) {
            gx0 += sred[0][c2 * 32 + b2];
            gx1 += sred[1][c2 * 32 + b2];
            gx2 += sred[2][c2 * 32 + b2];
        }
        const int o2 = b2 * 512 + j;
        float gh0 = b_hh[j], gh1 = b_hh[512 + j], gh2 = b_hh[1024 + j];
#pragma unroll
        for (int c2 = 0; c2 < 4; c2++) {
            gh0 += ghp[(c2 * 3 + 0) * 16384 + o2];
            gh1 += ghp[(c2 * 3 + 1) * 16384 + o2];
            gh2 += ghp[(c2 * 3 + 2) * 16384 + o2];
        }
        const float* gxe = Gxe + ((size_t)(b2 * T_ + t)) * 1536;
        gx0 += gxe[j]; gx1 += gxe[512 + j]; gx2 += gxe[1024 + j];
        const float r = sigmoid_fast(gx0 + gh0);
        const float z = sigmoid_fast(gx1 + gh1);
        const float n = tanh_fast(gx2 + r * gh2);
        const float hn = (1.f - z) * n + z * h[o2];
        h[o2] = hn;
        Hall[((size_t)b2 * T_ + t) * 512 + j] = f2bf(hn);
        if (t == T_ - 1) hf[o2] = hn;
    }
}

// ---------------------------------------------------------------------------
// Online log_softmax over V=32000 per row, in place. One block per row.
// (verbatim r0)
// ---------------------------------------------------------------------------
__global__ void k_logsoftmax(float* __restrict__ logits)
{
    __shared__ float rm[4], rs[4];
    const int row = blockIdx.x;
    float* p = logits + (size_t)row * V_;
    const int tid = threadIdx.x;

    float m = -1e30f, s = 0.f;
    for (int i = tid * 4; i < V_; i += 1024) {
        const float4 x = *(const float4*)(p + i);
        const float m4 = fmaxf(fmaxf(x.x, x.y), fmaxf(x.z, x.w));
        const float mn = fmaxf(m, m4);
        s = s * __expf(m - mn) + __expf(x.x - mn) + __expf(x.y - mn)
          + __expf(x.z - mn) + __expf(x.w - mn);
        m = mn;
    }
    for (int off = 32; off; off >>= 1) {
        const float m2 = __shfl_down(m, off), s2 = __shfl_down(s, off);
        const float mn = fmaxf(m, m2);
        s = s * __expf(m - mn) + s2 * __expf(m2 - mn);
        m = mn;
    }
    if ((tid & 63) == 0) { rm[tid >> 6] = m; rs[tid >> 6] = s; }
    __syncthreads();
    const float M = fmaxf(fmaxf(rm[0], rm[1]), fmaxf(rm[2], rm[3]));
    const float S = rs[0] * __expf(rm[0] - M) + rs[1] * __expf(rm[1] - M)
                  + rs[2] * __expf(rm[2] - M) + rs[3] * __expf(rm[3] - M);
    const float lse = M + __logf(S);

    for (int i = tid * 4; i < V_; i += 1024) {
        float4 x = *(const float4*)(p + i);
        x.x -= lse; x.y -= lse; x.z -= lse; x.w -= lse;
        *(float4*)(p + i) = x;
    }
}

// ---------------------------------------------------------------------------
extern "C" void kernel_launch(void* const* d_in, const int* in_sizes, int n_in,
                              void* d_out, int out_size, void* d_ws, size_t ws_size,
                              hipStream_t stream)
{
    const float* enc   = (const float*)d_in[0];   // [B,S,2H]
    const float* ehid  = (const float*)d_in[1];   // [1,B,2H]
    const int*   tgt   = (const int*)d_in[2];     // [B,T]
    const float* emb   = (const float*)d_in[3];   // [V,H]
    const float* Wa_w  = (const float*)d_in[4];   // [H,H]
    const float* Wa_b  = (const float*)d_in[5];
    const float* Ua_w  = (const float*)d_in[6];   // [H,2H]
    const float* Ua_b  = (const float*)d_in[7];
    const float* Va_w  = (const float*)d_in[8];   // [1,H]
    const float* Va_b  = (const float*)d_in[9];   // [1]
    const float* W_ih  = (const float*)d_in[10];  // [3H,3H]
    const float* b_ih  = (const float*)d_in[11];
    const float* W_hh  = (const float*)d_in[12];  // [3H,H]
    const float* b_hh  = (const float*)d_in[13];
    const float* Wh    = (const float*)d_in[14];  // [H,2H]
    const float* bh    = (const float*)d_in[15];
    const float* out_w = (const float*)d_in[16];  // [V,H]
    const float* out_b = (const float*)d_in[17];  // [V]

    float* outp = (float*)d_out;
    float* lp   = outp;                 // [B,T,V] = 32,768,000 floats
    float* hf   = outp + 32768000;      // [1,B,H]
    float* attn = outp + 32784384;      // [B,T,S]

    // Transient scratch inside the lp region (dead before the logits GEMM
    // overwrites all of lp):
    float* Gxe  = lp;                   // 1,572,864  [B*T, 3H] emb-part + b_ih
    float* Xemb = lp + 1572864;         //   524,288  [B*T, H]
    float* ghp  = lp + 2097152;         //   196,608  12 x [B*H]
    float* h0p  = lp + 2293760;         //    65,536  setup-only

    // Persistent ws (~5.4 MB, same layout as the verified r0 kernel)
    float* ws  = (float*)d_ws;
    float* h   = ws;                    // 16,384
    float* ctx = ws + 16384;            // 32,768
    float* ua  = ws + 49152;            // 1,048,576  [B*S, H]
    unsigned short* Hall = (unsigned short*)(ws + 1097728);  // [B*T, H] bf16

    // ---- setup ----
    k_h0part<<<256, 256, 0, stream>>>(ehid, Wh, h0p);
    k_h0fin<<<64, 256, 0, stream>>>(h0p, bh, h);
    k_gather<<<512, 256, 0, stream>>>(emb, tgt, Xemb);
    gemm_bt<false><<<dim3(16, 4), 256, 0, stream>>>(enc, Ua_w, Ua_b, ua,
                                                    2048, 512, 1024, 1024);
    gemm_bt<false><<<dim3(8, 12), 256, 0, stream>>>(Xemb, W_ih, b_ih, Gxe,
                                                    1024, 1536, 512, 1536);

    // ---- sequential scan: 2 launches per step ----
    for (int t = 0; t < T_; t++) {
        k_attn_gh<<<288, 256, 0, stream>>>(h, Wa_w, Wa_b, ua, Va_w, Va_b,
                                           enc, W_hh, ctx, ghp, attn, t);
        k_gx_fin<<<512, 256, 0, stream>>>(ctx, W_ih, ghp, Gxe, b_hh, h, Hall,
                                          hf, t);
    }

    // ---- logits + log_softmax ----
    gemm_bt_ml<true><<<250, 256, 0, stream>>>(Hall, out_w, out_b, lp,
                                              1024, V_, 512, 512);
    k_logsoftmax<<<1024, 256, 0, stream>>>(lp);
}

// Round 6
// 1828.890 us; speedup vs baseline: 3.1969x; 1.4952x over previous
//
#include <hip/hip_runtime.h>
#include <hip/hip_bf16.h>

// Problem dims (fixed)
#define B_ 32
#define S_ 64
#define H_ 512
#define T_ 32
#define V_ 32000

typedef __attribute__((ext_vector_type(8))) short bf16x8;
typedef __attribute__((ext_vector_type(4))) float f32x4;

static __device__ __forceinline__ unsigned short f2bf(float f) {
    unsigned int u = __float_as_uint(f);
    u += 0x7FFF + ((u >> 16) & 1);   // RNE
    return (unsigned short)(u >> 16);
}
static __device__ __forceinline__ float dot4(float4 a, float4 b) {
    return a.x * b.x + a.y * b.y + a.z * b.z + a.w * b.w;
}
static __device__ __forceinline__ float tanh_fast(float x) {
    x = fminf(fmaxf(x, -15.f), 15.f);
    float e = __expf(2.f * x);
    return (e - 1.f) / (e + 1.f);
}
static __device__ __forceinline__ float sigmoid_fast(float x) {
    return 1.f / (1.f + __expf(-x));
}

// ---------------------------------------------------------------------------
// C[m,n] = sum_k A[m,k] * B[n,k] + (bias ? bias[n] : 0)
// Tile 128x128, BK=32, 4 waves, 4x4 frags of 16x16x32 bf16 MFMA. (verified r0)
// ---------------------------------------------------------------------------
template <bool A_BF16>
__global__ __launch_bounds__(256, 2)
void gemm_bt(const void* __restrict__ Av, const float* __restrict__ Bm,
             const float* __restrict__ bias, float* __restrict__ C,
             int M, int N, int K, int Bld)
{
    __shared__ unsigned short As[128 * 32];
    __shared__ unsigned short Bs[128 * 32];

    const int m0 = blockIdx.x * 128;
    const int n0 = blockIdx.y * 128;
    const int tid  = threadIdx.x;
    const int lane = tid & 63;
    const int wave = tid >> 6;
    const int wm   = (wave & 1) * 64;
    const int wn   = (wave >> 1) * 64;
    const int quad = lane >> 4;   // 0..3
    const int l16  = lane & 15;

    f32x4 acc[4][4];
#pragma unroll
    for (int i = 0; i < 4; i++)
#pragma unroll
        for (int j = 0; j < 4; j++) acc[i][j] = (f32x4){0.f, 0.f, 0.f, 0.f};

    const int r0 = tid >> 2;  // 0..63 (row group)
    const int q4 = tid & 3;   // 0..3  (k sub-chunk of 8)

    for (int k0 = 0; k0 < K; k0 += 32) {
        __syncthreads();
#pragma unroll
        for (int rr = 0; rr < 2; rr++) {
            const int row = r0 + rr * 64;
            if (A_BF16) {
                const unsigned short* A16 = (const unsigned short*)Av;
                const uint4 v = *(const uint4*)(A16 + (size_t)(m0 + row) * K + k0 + q4 * 8);
                *(uint4*)(&As[row * 32 + q4 * 8]) = v;
            } else {
                const float* A32 = (const float*)Av;
                const float4 s0 = *(const float4*)(A32 + (size_t)(m0 + row) * K + k0 + q4 * 8);
                const float4 s1 = *(const float4*)(A32 + (size_t)(m0 + row) * K + k0 + q4 * 8 + 4);
                unsigned short tmp[8] = {f2bf(s0.x), f2bf(s0.y), f2bf(s0.z), f2bf(s0.w),
                                         f2bf(s1.x), f2bf(s1.y), f2bf(s1.z), f2bf(s1.w)};
                *(uint4*)(&As[row * 32 + q4 * 8]) = *(uint4*)tmp;
            }
            const float4 t0 = *(const float4*)(Bm + (size_t)(n0 + row) * Bld + k0 + q4 * 8);
            const float4 t1 = *(const float4*)(Bm + (size_t)(n0 + row) * Bld + k0 + q4 * 8 + 4);
            unsigned short tb[8] = {f2bf(t0.x), f2bf(t0.y), f2bf(t0.z), f2bf(t0.w),
                                    f2bf(t1.x), f2bf(t1.y), f2bf(t1.z), f2bf(t1.w)};
            *(uint4*)(&Bs[row * 32 + q4 * 8]) = *(uint4*)tb;
        }
        __syncthreads();

        bf16x8 af[4], bfr[4];
#pragma unroll
        for (int i = 0; i < 4; i++)
            af[i] = *(const bf16x8*)(&As[(wm + 16 * i + l16) * 32 + quad * 8]);
#pragma unroll
        for (int j = 0; j < 4; j++)
            bfr[j] = *(const bf16x8*)(&Bs[(wn + 16 * j + l16) * 32 + quad * 8]);
#pragma unroll
        for (int i = 0; i < 4; i++)
#pragma unroll
            for (int j = 0; j < 4; j++)
                acc[i][j] = __builtin_amdgcn_mfma_f32_16x16x32_bf16(af[i], bfr[j], acc[i][j], 0, 0, 0);
    }

#pragma unroll
    for (int i = 0; i < 4; i++)
#pragma unroll
        for (int j = 0; j < 4; j++)
#pragma unroll
            for (int r = 0; r < 4; r++) {
                const int m = m0 + wm + 16 * i + quad * 4 + r;
                const int n = n0 + wn + 16 * j + l16;
                C[(size_t)m * N + n] = acc[i][j][r] + (bias ? bias[n] : 0.f);
            }
}

// ---------------------------------------------------------------------------
// Logits GEMM: same body, A bf16, 1D grid of 2048 with XCD swizzle so all 8
// m-tiles of an n-tile land on ONE XCD (bid%8 = XCD round-robin) -> each
// out_w panel is fetched into exactly one L2 instead of 8.
// M=1024, N=32000 (250 n-tiles, guard), K=512.
// ---------------------------------------------------------------------------
__global__ __launch_bounds__(256, 2)
void gemm_logits(const unsigned short* __restrict__ A16, const float* __restrict__ Bm,
                 const float* __restrict__ bias, float* __restrict__ C)
{
    const int bid = blockIdx.x;          // 0..2047
    const int xcd = bid & 7;
    const int l   = bid >> 3;            // 0..255
    const int nt  = (l >> 3) * 8 + xcd;  // 0..255
    if (nt >= 250) return;
    const int m0 = (l & 7) * 128;
    const int n0 = nt * 128;
    const int M = 1024, N = V_, K = 512, Bld = 512;

    __shared__ unsigned short As[128 * 32];
    __shared__ unsigned short Bs[128 * 32];

    const int tid  = threadIdx.x;
    const int lane = tid & 63;
    const int wave = tid >> 6;
    const int wm   = (wave & 1) * 64;
    const int wn   = (wave >> 1) * 64;
    const int quad = lane >> 4;
    const int l16  = lane & 15;

    f32x4 acc[4][4];
#pragma unroll
    for (int i = 0; i < 4; i++)
#pragma unroll
        for (int j = 0; j < 4; j++) acc[i][j] = (f32x4){0.f, 0.f, 0.f, 0.f};

    const int r0 = tid >> 2;
    const int q4 = tid & 3;

    for (int k0 = 0; k0 < K; k0 += 32) {
        __syncthreads();
#pragma unroll
        for (int rr = 0; rr < 2; rr++) {
            const int row = r0 + rr * 64;
            const uint4 v = *(const uint4*)(A16 + (size_t)(m0 + row) * K + k0 + q4 * 8);
            *(uint4*)(&As[row * 32 + q4 * 8]) = v;
            const float4 t0 = *(const float4*)(Bm + (size_t)(n0 + row) * Bld + k0 + q4 * 8);
            const float4 t1 = *(const float4*)(Bm + (size_t)(n0 + row) * Bld + k0 + q4 * 8 + 4);
            unsigned short tb[8] = {f2bf(t0.x), f2bf(t0.y), f2bf(t0.z), f2bf(t0.w),
                                    f2bf(t1.x), f2bf(t1.y), f2bf(t1.z), f2bf(t1.w)};
            *(uint4*)(&Bs[row * 32 + q4 * 8]) = *(uint4*)tb;
        }
        __syncthreads();

        bf16x8 af[4], bfr[4];
#pragma unroll
        for (int i = 0; i < 4; i++)
            af[i] = *(const bf16x8*)(&As[(wm + 16 * i + l16) * 32 + quad * 8]);
#pragma unroll
        for (int j = 0; j < 4; j++)
            bfr[j] = *(const bf16x8*)(&Bs[(wn + 16 * j + l16) * 32 + quad * 8]);
#pragma unroll
        for (int i = 0; i < 4; i++)
#pragma unroll
            for (int j = 0; j < 4; j++)
                acc[i][j] = __builtin_amdgcn_mfma_f32_16x16x32_bf16(af[i], bfr[j], acc[i][j], 0, 0, 0);
    }

#pragma unroll
    for (int i = 0; i < 4; i++)
#pragma unroll
        for (int j = 0; j < 4; j++)
#pragma unroll
            for (int r = 0; r < 4; r++) {
                const int m = m0 + wm + 16 * i + quad * 4 + r;
                const int n = n0 + wn + 16 * j + l16;
                C[(size_t)m * N + n] = acc[i][j][r] + bias[n];
            }
}

// ---------------------------------------------------------------------------
// setup kernels (verbatim r0)
// ---------------------------------------------------------------------------
__global__ void k_h0part(const float* __restrict__ ehid, const float* __restrict__ Wh,
                         float* __restrict__ h0p)
{
    const int o = blockIdx.x * 256 + threadIdx.x;  // 65536
    const int b = o & 31, j = (o >> 5) & 511, c = o >> 14;
    const float* x = ehid + b * 1024 + c * 256;
    const float* w = Wh + (size_t)j * 1024 + c * 256;
    float s = 0.f;
#pragma unroll 8
    for (int k = 0; k < 256; k += 4)
        s += dot4(*(const float4*)(x + k), *(const float4*)(w + k));
    h0p[c * 16384 + b * 512 + j] = s;
}

__global__ void k_h0fin(const float* __restrict__ h0p, const float* __restrict__ bh,
                        float* __restrict__ h)
{
    const int o = blockIdx.x * 256 + threadIdx.x;  // 16384
    h[o] = bh[o & 511] + h0p[o] + h0p[16384 + o] + h0p[32768 + o] + h0p[49152 + o];
}

__global__ void k_gather(const float* __restrict__ emb, const int* __restrict__ tgt,
                         float* __restrict__ Xemb)
{
    const int o = blockIdx.x * 256 + threadIdx.x;  // 131072
    const int r = o >> 7, k4 = (o & 127) * 4;
    const int b = r >> 5, t = r & 31;
    const int tok = t ? tgt[b * T_ + t - 1] : 0;
    *(float4*)(Xemb + (size_t)r * 512 + k4) = *(const float4*)(emb + (size_t)tok * 512 + k4);
}

// ---------------------------------------------------------------------------
// Scan launch 1: 512 blocks x 256 threads.
//  blocks 0..255 : qp partials — VERBATIM r0 k_q (b-lane broadcast of Wa_w)
//  blocks 256..511: ghp partials — VERBATIM r0 k_ggx gh-half
// ---------------------------------------------------------------------------
__global__ __launch_bounds__(256)
void k_q_gh(const float* __restrict__ h, const float* __restrict__ Wa_w,
            const float* __restrict__ W_hh,
            float* __restrict__ qp, float* __restrict__ ghp)
{
    const int bid = blockIdx.x;
    const int tid = threadIdx.x;
    if (bid < 256) {
        const int o = bid * 256 + tid;                        // 0..65535
        const int b = o & 31, j = (o >> 5) & 511, c = o >> 14;
        const float* x = h + b * 512 + c * 128;
        const float* w = Wa_w + (size_t)j * 512 + c * 128;
        float s = 0.f;
#pragma unroll 8
        for (int k = 0; k < 128; k += 4)
            s += dot4(*(const float4*)(x + k), *(const float4*)(w + k));
        qp[c * 16384 + b * 512 + j] = s;
    } else {
        const int o = (bid - 256) * 256 + tid;                // 0..65535
        const int b = o & 31, j = (o >> 5) & 511, c = o >> 14;
        const float* x  = h + b * 512 + c * 128;
        const float* w0 = W_hh + (size_t)j * 512 + c * 128;
        const float* w1 = w0 + 512 * 512;
        const float* w2 = w1 + 512 * 512;
        float s0 = 0.f, s1 = 0.f, s2 = 0.f;
#pragma unroll 8
        for (int k = 0; k < 128; k += 4) {
            const float4 xv = *(const float4*)(x + k);
            s0 += dot4(xv, *(const float4*)(w0 + k));
            s1 += dot4(xv, *(const float4*)(w1 + k));
            s2 += dot4(xv, *(const float4*)(w2 + k));
        }
        const int ix = b * 512 + j;
        ghp[(c * 3 + 0) * 16384 + ix] = s0;
        ghp[(c * 3 + 1) * 16384 + ix] = s1;
        ghp[(c * 3 + 2) * 16384 + ix] = s2;
    }
}

// ---------------------------------------------------------------------------
// Scan launch 2: 32 blocks x 256 threads, block = batch b.
//  1) q = sum of qp partials + Wa_b           (r0 k_attn body)
//  2) scores + softmax -> wsm, attn_out       (r0 k_attn body)
//  3) gx[1536] = sum_s wsm[s] * ENC2[b,s,:]   (replaces ctx AND the gx GEMM;
//     ENC2 = enc @ W_ih[:,512:]^T precomputed — linearity of the GRU x-path)
//  4) finalize: gates + h update + Hall       (r0 k_fin math)
// ---------------------------------------------------------------------------
__global__ __launch_bounds__(256)
void k_attn_fin(const float* __restrict__ qp, const float* __restrict__ Wa_b,
                const float* __restrict__ ua, const float* __restrict__ Va_w,
                const float* __restrict__ Va_b, const float* __restrict__ ENC2,
                const float* __restrict__ ghp, const float* __restrict__ Gxe,
                const float* __restrict__ b_hh, float* __restrict__ h,
                unsigned short* __restrict__ Hall, float* __restrict__ attn_out,
                float* __restrict__ hf, int t)
{
    __shared__ float qs[512];
    __shared__ float parts[64][4];
    __shared__ float wsm[64];
    __shared__ float gxs[1536];

    const int b = blockIdx.x;
    const int tid = threadIdx.x;

    for (int i = tid; i < 512; i += 256) {
        const int ix = b * 512 + i;
        qs[i] = qp[ix] + qp[16384 + ix] + qp[32768 + ix] + qp[49152 + ix] + Wa_b[i];
    }
    __syncthreads();

    // scores (r0 body)
    {
        const int s = tid >> 2, p = tid & 3;
        const float* uar = ua + ((size_t)(b * 64 + s)) * 512 + p * 128;
        const float* vp = Va_w + p * 128;
        float acc = 0.f;
#pragma unroll 8
        for (int k = 0; k < 128; k += 4) {
            float4 u4 = *(const float4*)(uar + k);
            float4 v4 = *(const float4*)(vp + k);
            float4 q4 = *(const float4*)(&qs[p * 128 + k]);
            acc += v4.x * tanh_fast(q4.x + u4.x) + v4.y * tanh_fast(q4.y + u4.y)
                 + v4.z * tanh_fast(q4.z + u4.z) + v4.w * tanh_fast(q4.w + u4.w);
        }
        parts[s][p] = acc;
    }
    __syncthreads();

    if (tid < 64) {
        float sc = parts[tid][0] + parts[tid][1] + parts[tid][2] + parts[tid][3] + Va_b[0];
        float mx = sc;
        for (int off = 32; off; off >>= 1) mx = fmaxf(mx, __shfl_down(mx, off));
        mx = __shfl(mx, 0);
        float e = __expf(sc - mx);
        float sum = e;
        for (int off = 32; off; off >>= 1) sum += __shfl_down(sum, off);
        sum = __shfl(sum, 0);
        float w = e / sum;
        wsm[tid] = w;
        attn_out[((size_t)b * T_ + t) * 64 + tid] = w;
    }
    __syncthreads();

    // gx-sum over ENC2 rows: 384 float4 columns, coalesced per wave
    for (int i4 = tid; i4 < 384; i4 += 256) {
        float4 a = {0.f, 0.f, 0.f, 0.f};
        const float* eb = ENC2 + ((size_t)b * 64) * 1536 + i4 * 4;
        for (int s2 = 0; s2 < 64; s2++) {
            const float w = wsm[s2];
            const float4 e4 = *(const float4*)(eb + (size_t)s2 * 1536);
            a.x += w * e4.x; a.y += w * e4.y; a.z += w * e4.z; a.w += w * e4.w;
        }
        *(float4*)(&gxs[i4 * 4]) = a;
    }
    __syncthreads();

    // finalize (r0 k_fin math), 2 j per thread
    for (int j = tid; j < 512; j += 256) {
        const int o2 = b * 512 + j;
        float gh0 = b_hh[j], gh1 = b_hh[512 + j], gh2 = b_hh[1024 + j];
#pragma unroll
        for (int c2 = 0; c2 < 4; c2++) {
            gh0 += ghp[(c2 * 3 + 0) * 16384 + o2];
            gh1 += ghp[(c2 * 3 + 1) * 16384 + o2];
            gh2 += ghp[(c2 * 3 + 2) * 16384 + o2];
        }
        const float* gxe = Gxe + ((size_t)(b * T_ + t)) * 1536;
        const float gx0 = gxs[j] + gxe[j];
        const float gx1 = gxs[512 + j] + gxe[512 + j];
        const float gx2 = gxs[1024 + j] + gxe[1024 + j];
        const float r = sigmoid_fast(gx0 + gh0);
        const float z = sigmoid_fast(gx1 + gh1);
        const float n = tanh_fast(gx2 + r * gh2);
        const float hn = (1.f - z) * n + z * h[o2];
        h[o2] = hn;
        Hall[((size_t)b * T_ + t) * 512 + j] = f2bf(hn);
        if (t == T_ - 1) hf[o2] = hn;
    }
}

// ---------------------------------------------------------------------------
// Online log_softmax over V=32000 per row, in place. (verbatim r0)
// ---------------------------------------------------------------------------
__global__ void k_logsoftmax(float* __restrict__ logits)
{
    __shared__ float rm[4], rs[4];
    const int row = blockIdx.x;
    float* p = logits + (size_t)row * V_;
    const int tid = threadIdx.x;

    float m = -1e30f, s = 0.f;
    for (int i = tid * 4; i < V_; i += 1024) {
        const float4 x = *(const float4*)(p + i);
        const float m4 = fmaxf(fmaxf(x.x, x.y), fmaxf(x.z, x.w));
        const float mn = fmaxf(m, m4);
        s = s * __expf(m - mn) + __expf(x.x - mn) + __expf(x.y - mn)
          + __expf(x.z - mn) + __expf(x.w - mn);
        m = mn;
    }
    for (int off = 32; off; off >>= 1) {
        const float m2 = __shfl_down(m, off), s2 = __shfl_down(s, off);
        const float mn = fmaxf(m, m2);
        s = s * __expf(m - mn) + s2 * __expf(m2 - mn);
        m = mn;
    }
    if ((tid & 63) == 0) { rm[tid >> 6] = m; rs[tid >> 6] = s; }
    __syncthreads();
    const float M = fmaxf(fmaxf(rm[0], rm[1]), fmaxf(rm[2], rm[3]));
    const float S = rs[0] * __expf(rm[0] - M) + rs[1] * __expf(rm[1] - M)
                  + rs[2] * __expf(rm[2] - M) + rs[3] * __expf(rm[3] - M);
    const float lse = M + __logf(S);

    for (int i = tid * 4; i < V_; i += 1024) {
        float4 x = *(const float4*)(p + i);
        x.x -= lse; x.y -= lse; x.z -= lse; x.w -= lse;
        *(float4*)(p + i) = x;
    }
}

// ---------------------------------------------------------------------------
extern "C" void kernel_launch(void* const* d_in, const int* in_sizes, int n_in,
                              void* d_out, int out_size, void* d_ws, size_t ws_size,
                              hipStream_t stream)
{
    const float* enc   = (const float*)d_in[0];   // [B,S,2H]
    const float* ehid  = (const float*)d_in[1];   // [1,B,2H]
    const int*   tgt   = (const int*)d_in[2];     // [B,T]
    const float* emb   = (const float*)d_in[3];   // [V,H]
    const float* Wa_w  = (const float*)d_in[4];   // [H,H]
    const float* Wa_b  = (const float*)d_in[5];
    const float* Ua_w  = (const float*)d_in[6];   // [H,2H]
    const float* Ua_b  = (const float*)d_in[7];
    const float* Va_w  = (const float*)d_in[8];   // [1,H]
    const float* Va_b  = (const float*)d_in[9];   // [1]
    const float* W_ih  = (const float*)d_in[10];  // [3H,3H]
    const float* b_ih  = (const float*)d_in[11];
    const float* W_hh  = (const float*)d_in[12];  // [3H,H]
    const float* b_hh  = (const float*)d_in[13];
    const float* Wh    = (const float*)d_in[14];  // [H,2H]
    const float* bh    = (const float*)d_in[15];
    const float* out_w = (const float*)d_in[16];  // [V,H]
    const float* out_b = (const float*)d_in[17];  // [V]

    float* outp = (float*)d_out;
    float* lp   = outp;                 // [B,T,V] = 32,768,000 floats
    float* hf   = outp + 32768000;      // [1,B,H]
    float* attn = outp + 32784384;      // [B,T,S]

    // Transient scratch inside the lp region (all dead before the logits GEMM
    // overwrites lp):
    float* Gxe  = lp;                   // 1,572,864  [B*T, 3H]  emb-part + b_ih
    float* Xemb = lp + 1572864;         //   524,288  [B*T, H]
    float* ghp  = lp + 2097152;         //   196,608  12 x [B*H]
    float* qp   = lp + 2293760;         //    65,536  4 x [B*H]
    float* ENC2 = lp + 2359296;         // 3,145,728  [B*S, 3H]  enc @ W_ihc^T
    float* h0p  = lp + 5505024;         //    65,536  setup-only

    // Persistent ws (same layout as verified r0)
    float* ws  = (float*)d_ws;
    float* h   = ws;                    // 16,384
    float* ua  = ws + 49152;            // 1,048,576  [B*S, H]
    unsigned short* Hall = (unsigned short*)(ws + 1097728);  // [B*T, H] bf16

    // ---- setup ----
    k_h0part<<<256, 256, 0, stream>>>(ehid, Wh, h0p);
    k_h0fin<<<64, 256, 0, stream>>>(h0p, bh, h);
    k_gather<<<512, 256, 0, stream>>>(emb, tgt, Xemb);
    gemm_bt<false><<<dim3(16, 4), 256, 0, stream>>>(enc, Ua_w, Ua_b, ua,
                                                    2048, 512, 1024, 1024);
    gemm_bt<false><<<dim3(8, 12), 256, 0, stream>>>(Xemb, W_ih, b_ih, Gxe,
                                                    1024, 1536, 512, 1536);
    // ENC2 = enc @ W_ih[:,512:]^T  (no bias)
    gemm_bt<false><<<dim3(16, 12), 256, 0, stream>>>(enc, W_ih + 512, nullptr,
                                                     ENC2, 2048, 1536, 1024, 1536);

    // ---- sequential scan: 2 launches per step ----
    for (int t = 0; t < T_; t++) {
        k_q_gh<<<512, 256, 0, stream>>>(h, Wa_w, W_hh, qp, ghp);
        k_attn_fin<<<32, 256, 0, stream>>>(qp, Wa_b, ua, Va_w, Va_b, ENC2,
                                           ghp, Gxe, b_hh, h, Hall, attn, hf, t);
    }

    // ---- logits + log_softmax ----
    gemm_logits<<<2048, 256, 0, stream>>>(Hall, out_w, out_b, lp);
    k_logsoftmax<<<1024, 256, 0, stream>>>(lp);
}